// Round 6
// baseline (147.892 us; speedup 1.0000x reference)
//
#include <hip/hip_runtime.h>
#include <math.h>

#define NNODES 50000
#define NEDGES 800000
#define NBASIS 10
#define NT 2048
#define RCUT 3.0f
#define NCHUNK 196   // ceil(50000/256)

// ws layout (bytes):
//   tab      @ 0x000000 : float[NT*128]          (1 MB)
//   tabP     @ 0x100000 : float2[(NT-1)*128]     (2 MB)
//   hist     @ 0x300000 : int[50000]
//   row_st   @ 0x340000 : int[50001]
//   cursor   @ 0x380000 : int[50000]
//   bsums    @ 0x3C0000 : int[256]
//   bscan    @ 0x3C1000 : int[256]
//   actbits  @ 0x3D0000 : ull[12500]
//   csrS     @ 0x400000 : int[800000]            (3.2 MB)
//   csrG     @ 0x800000 : float4[800000]         (12.8 MB)

__global__ __launch_bounds__(128) void table_kernel(
    const float* __restrict__ W1, const float* __restrict__ W2,
    float* __restrict__ tab, int* __restrict__ hist)
{
    int gid = blockIdx.x * 128 + threadIdx.x;
    if (gid < NNODES) hist[gid] = 0;

    __shared__ float hs[100];
    const int i = blockIdx.x;
    const int t = threadIdx.x;
    const float r = (float)i * (RCUT / (float)(NT - 1));
    if (t < 100) {
        const float step = 2.0f / 9.0f, istep = 4.5f, cemb = 2.8234622f;
        float pre = 0.f;
        #pragma unroll
        for (int j = 0; j < NBASIS; ++j) {
            float dv = (r - (float)j * step) * istep;
            pre += expf(-dv * dv) * cemb * W1[j * 100 + t];
        }
        float z = pre * 0.316227766f;
        hs[t] = z / (1.0f + expf(-z));
    }
    __syncthreads();
    float acc = 0.f;
    for (int k = 0; k < 100; ++k) acc += hs[k] * W2[k * 128 + t];
    float sc = 0.1f * 0.25f;                       // /sqrt(100) * /sqrt(16)
    if (t >= 32 && t < 64) sc *= 1.7320508075688772f;  // sqrt(3) for cat-2 cols
    tab[i * 128 + t] = acc * sc;
}

// pair rows: tabP[i*256 + 2m+sel] = tab[(i+sel)*128 + m]
__global__ __launch_bounds__(256) void pack_kernel(
    const float* __restrict__ tab, float* __restrict__ tabP)
{
    int i = blockIdx.x;
    int t = threadIdx.x;
    tabP[i * 256 + t] = tab[(i + (t & 1)) * 128 + (t >> 1)];
}

__global__ __launch_bounds__(256) void hist_kernel(
    const float* __restrict__ pos,
    const int* __restrict__ esrc, const int* __restrict__ edst,
    int* __restrict__ hist, unsigned long long* __restrict__ actbits)
{
    int e = blockIdx.x * 256 + threadIdx.x;
    bool act = false;
    int d = 0;
    if (e < NEDGES) {
        int s = esrc[e]; d = edst[e];
        float vx = pos[3*s]   - pos[3*d];
        float vy = pos[3*s+1] - pos[3*d+1];
        float vz = pos[3*s+2] - pos[3*d+2];
        act = (vx*vx + vy*vy + vz*vz) <= RCUT * RCUT;
    }
    unsigned long long mask = __ballot(act);
    if ((threadIdx.x & 63) == 0) actbits[e >> 6] = mask;
    if (act) atomicAdd(&hist[d], 1);
}

__global__ __launch_bounds__(256) void scanA_kernel(const int* __restrict__ hist,
                                                    int* __restrict__ bsums) {
    __shared__ int s[256];
    int i = blockIdx.x * 256 + threadIdx.x;
    int v = (i < NNODES) ? hist[i] : 0;
    s[threadIdx.x] = v;
    __syncthreads();
    for (int off = 128; off > 0; off >>= 1) {
        if (threadIdx.x < off) s[threadIdx.x] += s[threadIdx.x + off];
        __syncthreads();
    }
    if (threadIdx.x == 0) bsums[blockIdx.x] = s[0];
}

__global__ __launch_bounds__(256) void scanB_kernel(const int* __restrict__ bsums,
                                                    int* __restrict__ bscan) {
    __shared__ int s[256];
    int t = threadIdx.x;
    int v = (t < NCHUNK) ? bsums[t] : 0;
    s[t] = v;
    __syncthreads();
    for (int off = 1; off < 256; off <<= 1) {
        int u = (t >= off) ? s[t - off] : 0;
        __syncthreads();
        s[t] += u;
        __syncthreads();
    }
    if (t < NCHUNK) bscan[t] = s[t] - v;   // exclusive
}

__global__ __launch_bounds__(256) void scanC_kernel(
    const int* __restrict__ hist, const int* __restrict__ bscan,
    int* __restrict__ row_st, int* __restrict__ cursor)
{
    __shared__ int s[256];
    int i = blockIdx.x * 256 + threadIdx.x;
    int t = threadIdx.x;
    int v = (i < NNODES) ? hist[i] : 0;
    s[t] = v;
    __syncthreads();
    for (int off = 1; off < 256; off <<= 1) {
        int u = (t >= off) ? s[t - off] : 0;
        __syncthreads();
        s[t] += u;
        __syncthreads();
    }
    int excl = s[t] - v + bscan[blockIdx.x];
    if (i < NNODES) { row_st[i] = excl; cursor[i] = excl; }
    if (i == NNODES - 1) row_st[NNODES] = excl + v;
}

__global__ __launch_bounds__(256) void fill_kernel(
    const float* __restrict__ pos,
    const int* __restrict__ esrc, const int* __restrict__ edst,
    const unsigned long long* __restrict__ actbits,
    int* __restrict__ cursor, float4* __restrict__ csrG, int* __restrict__ csrS)
{
    int e = blockIdx.x * 256 + threadIdx.x;
    if (e >= NEDGES) return;
    if (!((actbits[e >> 6] >> (e & 63)) & 1ull)) return;
    int s = esrc[e], d = edst[e];
    float vx = pos[3*s]   - pos[3*d];
    float vy = pos[3*s+1] - pos[3*d+1];
    float vz = pos[3*s+2] - pos[3*d+2];
    float r = sqrtf(vx*vx + vy*vy + vz*vz + 1e-12f);
    float inv = 1.0f / r;
    const float iscale = (float)(NT - 1) / RCUT;
    int slot = atomicAdd(&cursor[d], 1);
    csrG[slot] = make_float4(vx * inv, vy * inv, vz * inv, r * iscale);
    csrS[slot] = s;
}

// wave handles 4 consecutive nodes -> 4 independent edge chains per lane
__global__ __launch_bounds__(256) void gather_kernel(
    const float* __restrict__ x, const float2* __restrict__ tabP,
    const int* __restrict__ row_st,
    const float4* __restrict__ csrG, const int* __restrict__ csrS,
    float* __restrict__ out)
{
    const int lane = threadIdx.x & 63;
    const int wid  = threadIdx.x >> 6;
    const int node0 = (blockIdx.x * 4 + wid) * 4;
    const bool lo = lane < 32;

    // j0: f = lane        -> cat0 (lo) / cat1 (hi)
    const int m0  = lo ? lane : 64 + lane;
    const int xi0 = lo ? lane : 3 * lane - 64;
    // j1: f = 64 + lane   -> cat2, g = lane
    const int uu1 = lane / 3;
    const int m1 = 32 + uu1, xi1 = uu1, c1 = lane - 3 * uu1;
    // j2: f = 128 + lane  -> cat2 (lo) / cat3 (hi)
    const int uu2a = (64 + lane) / 3;
    const int m2  = lo ? 32 + uu2a : 64 + (lane - 32) / 3;
    const int xi2 = lo ? uu2a : lane;
    const int c2  = (64 + lane) - 3 * uu2a;
    // j3: f = 192 + lane  -> cat3, g = 32 + lane
    const int uu3 = (32 + lane) / 3;
    const int m3 = 64 + uu3, xi3 = 64 + lane;

    int beg[4], deg[4];
    #pragma unroll
    for (int c = 0; c < 4; ++c) {
        int n = node0 + c;
        if (n < NNODES) { int b = row_st[n]; beg[c] = b; deg[c] = row_st[n + 1] - b; }
        else            { beg[c] = 0; deg[c] = 0; }
    }
    const int maxd = max(max(deg[0], deg[1]), max(deg[2], deg[3]));

    float acc[4][4];
    #pragma unroll
    for (int c = 0; c < 4; ++c)
        #pragma unroll
        for (int j = 0; j < 4; ++j) acc[c][j] = 0.f;

    float4 g[4]; int s[4];
    #pragma unroll
    for (int c = 0; c < 4; ++c) {
        if (deg[c] > 0) { g[c] = csrG[beg[c]]; s[c] = csrS[beg[c]]; }
    }

    for (int k = 0; k < maxd; ++k) {
        #pragma unroll
        for (int c = 0; c < 4; ++c) {
            if (k < deg[c]) {                       // wave-uniform guard
                const float4 gc = g[c]; const int sc = s[c];
                if (k + 1 < deg[c]) { g[c] = csrG[beg[c] + k + 1]; s[c] = csrS[beg[c] + k + 1]; }
                const int ii = min((int)gc.w, NT - 2);
                const float fr = gc.w - (float)ii;
                const float2* tp = tabP + (size_t)ii * 128;
                const float2 p0 = tp[m0], p1 = tp[m1], p2 = tp[m2], p3 = tp[m3];
                const float* xr = x + (size_t)sc * 128;
                const float w0 = p0.x + (p0.y - p0.x) * fr;
                const float w1 = p1.x + (p1.y - p1.x) * fr;
                const float w2 = p2.x + (p2.y - p2.x) * fr;
                const float w3 = p3.x + (p3.y - p3.x) * fr;
                const float u1 = (c1 == 0) ? gc.x : (c1 == 1) ? gc.y : gc.z;
                if (lo) {
                    acc[c][0] += w0 * xr[xi0];
                    const float u2 = (c2 == 0) ? gc.x : (c2 == 1) ? gc.y : gc.z;
                    acc[c][2] += w2 * xr[xi2] * u2;
                } else {
                    acc[c][0] += w0 * (xr[xi0] * gc.x + xr[xi0 + 1] * gc.y + xr[xi0 + 2] * gc.z);
                    acc[c][2] += w2 * xr[xi2];
                }
                acc[c][1] += w1 * xr[xi1] * u1;
                acc[c][3] += w3 * xr[xi3];
            }
        }
    }

    #pragma unroll
    for (int c = 0; c < 4; ++c) {
        int n = node0 + c;
        if (n < NNODES) {
            float* orow = out + (size_t)n * 256;
            orow[lane]       = acc[c][0];
            orow[64 + lane]  = acc[c][1];
            orow[128 + lane] = acc[c][2];
            orow[192 + lane] = acc[c][3];
        }
    }
}

extern "C" void kernel_launch(void* const* d_in, const int* in_sizes, int n_in,
                              void* d_out, int out_size, void* d_ws, size_t ws_size,
                              hipStream_t stream) {
    const float* pos = (const float*)d_in[0];
    const float* x   = (const float*)d_in[1];
    const float* W1  = (const float*)d_in[2];
    const float* W2  = (const float*)d_in[3];
    const int* esrc  = (const int*)d_in[4];
    const int* edst  = (const int*)d_in[5];
    float* out = (float*)d_out;

    char* wsb = (char*)d_ws;
    float* tab   = (float*)wsb;
    float* tabP  = (float*)(wsb + 0x100000);
    int* hist    = (int*)(wsb + 0x300000);
    int* row_st  = (int*)(wsb + 0x340000);
    int* cursor  = (int*)(wsb + 0x380000);
    int* bsums   = (int*)(wsb + 0x3C0000);
    int* bscan   = (int*)(wsb + 0x3C1000);
    unsigned long long* actbits = (unsigned long long*)(wsb + 0x3D0000);
    int* csrS    = (int*)(wsb + 0x400000);
    float4* csrG = (float4*)(wsb + 0x800000);

    table_kernel<<<NT, 128, 0, stream>>>(W1, W2, tab, hist);
    pack_kernel<<<NT - 1, 256, 0, stream>>>(tab, tabP);
    hist_kernel<<<(NEDGES + 255) / 256, 256, 0, stream>>>(pos, esrc, edst, hist, actbits);
    scanA_kernel<<<NCHUNK, 256, 0, stream>>>(hist, bsums);
    scanB_kernel<<<1, 256, 0, stream>>>(bsums, bscan);
    scanC_kernel<<<NCHUNK, 256, 0, stream>>>(hist, bscan, row_st, cursor);
    fill_kernel<<<(NEDGES + 255) / 256, 256, 0, stream>>>(pos, esrc, edst, actbits, cursor, csrG, csrS);
    // 16 nodes per block (4 waves x 4 nodes)
    gather_kernel<<<(NNODES + 15) / 16, 256, 0, stream>>>(x, (const float2*)tabP, row_st, csrG, csrS, out);
}

// Round 7
// 96.576 us; speedup vs baseline: 1.5313x; 1.5313x over previous
//
#include <hip/hip_runtime.h>
#include <math.h>

#define NNODES 50000
#define NEDGES 800000
#define NBASIS 10
#define NT 2048
#define RCUT 3.0f
#define NCHUNK 196   // ceil(50000/256)

// ws layout (bytes):
//   tab      @ 0x000000 : float[NT*128]          (1 MB)
//   tabP     @ 0x100000 : float2[(NT-1)*128]     (2 MB)
//   hist     @ 0x300000 : int[50000]
//   row_st   @ 0x340000 : int[50001]
//   cursor   @ 0x380000 : int[50000]
//   bsums    @ 0x3C0000 : int[256]
//   bscan    @ 0x3C1000 : int[256]
//   actbits  @ 0x3D0000 : ull[12500]
//   csrS     @ 0x400000 : int[800000]            (3.2 MB)
//   csrG     @ 0x800000 : float4[800000]         (12.8 MB)

__global__ __launch_bounds__(128) void table_kernel(
    const float* __restrict__ W1, const float* __restrict__ W2,
    float* __restrict__ tab, int* __restrict__ hist)
{
    int gid = blockIdx.x * 128 + threadIdx.x;
    if (gid < NNODES) hist[gid] = 0;

    __shared__ float hs[100];
    const int i = blockIdx.x;
    const int t = threadIdx.x;
    const float r = (float)i * (RCUT / (float)(NT - 1));
    if (t < 100) {
        const float step = 2.0f / 9.0f, istep = 4.5f, cemb = 2.8234622f;
        float pre = 0.f;
        #pragma unroll
        for (int j = 0; j < NBASIS; ++j) {
            float dv = (r - (float)j * step) * istep;
            pre += expf(-dv * dv) * cemb * W1[j * 100 + t];
        }
        float z = pre * 0.316227766f;
        hs[t] = z / (1.0f + expf(-z));
    }
    __syncthreads();
    float acc = 0.f;
    for (int k = 0; k < 100; ++k) acc += hs[k] * W2[k * 128 + t];
    float sc = 0.1f * 0.25f;                       // /sqrt(100) * /sqrt(16)
    if (t >= 32 && t < 64) sc *= 1.7320508075688772f;  // sqrt(3) for cat-2 cols
    tab[i * 128 + t] = acc * sc;
}

// pair rows: tabP[i*256 + 2m+sel] = tab[(i+sel)*128 + m]
__global__ __launch_bounds__(256) void pack_kernel(
    const float* __restrict__ tab, float* __restrict__ tabP)
{
    int i = blockIdx.x;
    int t = threadIdx.x;
    tabP[i * 256 + t] = tab[(i + (t & 1)) * 128 + (t >> 1)];
}

__global__ __launch_bounds__(256) void hist_kernel(
    const float* __restrict__ pos,
    const int* __restrict__ esrc, const int* __restrict__ edst,
    int* __restrict__ hist, unsigned long long* __restrict__ actbits)
{
    int e = blockIdx.x * 256 + threadIdx.x;
    bool act = false;
    int d = 0;
    if (e < NEDGES) {
        int s = esrc[e]; d = edst[e];
        float vx = pos[3*s]   - pos[3*d];
        float vy = pos[3*s+1] - pos[3*d+1];
        float vz = pos[3*s+2] - pos[3*d+2];
        act = (vx*vx + vy*vy + vz*vz) <= RCUT * RCUT;
    }
    unsigned long long mask = __ballot(act);
    if ((threadIdx.x & 63) == 0) actbits[e >> 6] = mask;
    if (act) atomicAdd(&hist[d], 1);
}

__global__ __launch_bounds__(256) void scanA_kernel(const int* __restrict__ hist,
                                                    int* __restrict__ bsums) {
    __shared__ int s[256];
    int i = blockIdx.x * 256 + threadIdx.x;
    int v = (i < NNODES) ? hist[i] : 0;
    s[threadIdx.x] = v;
    __syncthreads();
    for (int off = 128; off > 0; off >>= 1) {
        if (threadIdx.x < off) s[threadIdx.x] += s[threadIdx.x + off];
        __syncthreads();
    }
    if (threadIdx.x == 0) bsums[blockIdx.x] = s[0];
}

__global__ __launch_bounds__(256) void scanB_kernel(const int* __restrict__ bsums,
                                                    int* __restrict__ bscan) {
    __shared__ int s[256];
    int t = threadIdx.x;
    int v = (t < NCHUNK) ? bsums[t] : 0;
    s[t] = v;
    __syncthreads();
    for (int off = 1; off < 256; off <<= 1) {
        int u = (t >= off) ? s[t - off] : 0;
        __syncthreads();
        s[t] += u;
        __syncthreads();
    }
    if (t < NCHUNK) bscan[t] = s[t] - v;   // exclusive
}

__global__ __launch_bounds__(256) void scanC_kernel(
    const int* __restrict__ hist, const int* __restrict__ bscan,
    int* __restrict__ row_st, int* __restrict__ cursor)
{
    __shared__ int s[256];
    int i = blockIdx.x * 256 + threadIdx.x;
    int t = threadIdx.x;
    int v = (i < NNODES) ? hist[i] : 0;
    s[t] = v;
    __syncthreads();
    for (int off = 1; off < 256; off <<= 1) {
        int u = (t >= off) ? s[t - off] : 0;
        __syncthreads();
        s[t] += u;
        __syncthreads();
    }
    int excl = s[t] - v + bscan[blockIdx.x];
    if (i < NNODES) { row_st[i] = excl; cursor[i] = excl; }
    if (i == NNODES - 1) row_st[NNODES] = excl + v;
}

__global__ __launch_bounds__(256) void fill_kernel(
    const float* __restrict__ pos,
    const int* __restrict__ esrc, const int* __restrict__ edst,
    const unsigned long long* __restrict__ actbits,
    int* __restrict__ cursor, float4* __restrict__ csrG, int* __restrict__ csrS)
{
    int e = blockIdx.x * 256 + threadIdx.x;
    if (e >= NEDGES) return;
    if (!((actbits[e >> 6] >> (e & 63)) & 1ull)) return;
    int s = esrc[e], d = edst[e];
    float vx = pos[3*s]   - pos[3*d];
    float vy = pos[3*s+1] - pos[3*d+1];
    float vz = pos[3*s+2] - pos[3*d+2];
    float r = sqrtf(vx*vx + vy*vy + vz*vz + 1e-12f);
    float inv = 1.0f / r;
    const float iscale = (float)(NT - 1) / RCUT;
    int slot = atomicAdd(&cursor[d], 1);
    csrG[slot] = make_float4(vx * inv, vy * inv, vz * inv, r * iscale);
    csrS[slot] = s;
}

// wave-per-node, branchless depth-2 software pipeline
__global__ __launch_bounds__(256) void gather_kernel(
    const float* __restrict__ x, const float2* __restrict__ tabP,
    const int* __restrict__ row_st,
    const float4* __restrict__ csrG, const int* __restrict__ csrS,
    float* __restrict__ out)
{
    const int lane = threadIdx.x & 63;
    const int node = blockIdx.x * 4 + (threadIdx.x >> 6);
    const bool lo = lane < 32;

    // j0: f = lane        -> cat0 (lo) / cat1 (hi)
    const int m0  = lo ? lane : 64 + lane;
    const int xi0 = lo ? lane : 3 * lane - 64;
    // j1: f = 64 + lane   -> cat2, g = lane
    const int uu1 = lane / 3;
    const int m1 = 32 + uu1, xi1 = uu1, c1 = lane - 3 * uu1;
    // j2: f = 128 + lane  -> cat2 (lo) / cat3 (hi)
    const int uu2a = (64 + lane) / 3;
    const int m2  = lo ? 32 + uu2a : 64 + (lane - 32) / 3;
    const int xi2 = lo ? uu2a : lane;
    const int c2  = (64 + lane) - 3 * uu2a;
    // j3: f = 192 + lane  -> cat3, g = 32 + lane
    const int uu3 = (32 + lane) / 3;
    const int m3 = 64 + uu3, xi3 = 64 + lane;

    const int beg = row_st[node];
    const int deg = row_st[node + 1] - beg;
    float* orow = out + (size_t)node * 256;
    if (deg == 0) {          // wave-uniform
        orow[lane] = 0.f; orow[64 + lane] = 0.f;
        orow[128 + lane] = 0.f; orow[192 + lane] = 0.f;
        return;
    }

    // ---- prologue: edge-0 value loads (A-state), edge-1 geometry
    float4 gA = csrG[beg];
    int    sA = csrS[beg];
    int   iiA = min((int)gA.w, NT - 2);
    float frA = gA.w - (float)iiA;
    const float2* tpA = tabP + (size_t)iiA * 128;
    float2 pA0 = tpA[m0], pA1 = tpA[m1], pA2 = tpA[m2], pA3 = tpA[m3];
    const float* xrA = x + (size_t)sA * 128;
    float xA0 = xrA[xi0], xA1 = xrA[xi0 + 1], xA2 = xrA[xi0 + 2];
    float xAb = xrA[xi1], xAc = xrA[xi2], xAd = xrA[xi3];

    int nidx = beg + min(1, deg - 1);
    float4 gN = csrG[nidx];
    int    sN = csrS[nidx];

    float a0 = 0.f, a1 = 0.f, a2 = 0.f, a3 = 0.f;

    for (int k = 0; k < deg; ++k) {
        // issue value loads for edge k+1 (B-state), clamped — no branches
        int   iiB = min((int)gN.w, NT - 2);
        float frB = gN.w - (float)iiB;
        const float2* tpB = tabP + (size_t)iiB * 128;
        float2 pB0 = tpB[m0], pB1 = tpB[m1], pB2 = tpB[m2], pB3 = tpB[m3];
        const float* xrB = x + (size_t)sN * 128;
        float xB0 = xrB[xi0], xB1 = xrB[xi0 + 1], xB2 = xrB[xi0 + 2];
        float xBb = xrB[xi1], xBc = xrB[xi2], xBd = xrB[xi3];
        // geometry prefetch for edge k+2 (clamped)
        int nn = beg + min(k + 2, deg - 1);
        float4 gNN = csrG[nn];
        int    sNN = csrS[nn];

        // compute edge k from A-state (loads issued last iteration)
        float w0 = pA0.x + (pA0.y - pA0.x) * frA;
        float w1 = pA1.x + (pA1.y - pA1.x) * frA;
        float w2 = pA2.x + (pA2.y - pA2.x) * frA;
        float w3 = pA3.x + (pA3.y - pA3.x) * frA;
        float u1 = (c1 == 0) ? gA.x : (c1 == 1) ? gA.y : gA.z;
        float u2 = (c2 == 0) ? gA.x : (c2 == 1) ? gA.y : gA.z;
        float dotv = xA0 * gA.x + xA1 * gA.y + xA2 * gA.z;
        a0 += w0 * (lo ? xA0 : dotv);
        a2 += w2 * (lo ? xAc * u2 : xAc);
        a1 += w1 * xAb * u1;
        a3 += w3 * xAd;

        // rotate B -> A, NN -> N
        gA = gN; frA = frB;
        pA0 = pB0; pA1 = pB1; pA2 = pB2; pA3 = pB3;
        xA0 = xB0; xA1 = xB1; xA2 = xB2;
        xAb = xBb; xAc = xBc; xAd = xBd;
        gN = gNN; sN = sNN;
    }

    orow[lane]       = a0;
    orow[64 + lane]  = a1;
    orow[128 + lane] = a2;
    orow[192 + lane] = a3;
}

extern "C" void kernel_launch(void* const* d_in, const int* in_sizes, int n_in,
                              void* d_out, int out_size, void* d_ws, size_t ws_size,
                              hipStream_t stream) {
    const float* pos = (const float*)d_in[0];
    const float* x   = (const float*)d_in[1];
    const float* W1  = (const float*)d_in[2];
    const float* W2  = (const float*)d_in[3];
    const int* esrc  = (const int*)d_in[4];
    const int* edst  = (const int*)d_in[5];
    float* out = (float*)d_out;

    char* wsb = (char*)d_ws;
    float* tab   = (float*)wsb;
    float* tabP  = (float*)(wsb + 0x100000);
    int* hist    = (int*)(wsb + 0x300000);
    int* row_st  = (int*)(wsb + 0x340000);
    int* cursor  = (int*)(wsb + 0x380000);
    int* bsums   = (int*)(wsb + 0x3C0000);
    int* bscan   = (int*)(wsb + 0x3C1000);
    unsigned long long* actbits = (unsigned long long*)(wsb + 0x3D0000);
    int* csrS    = (int*)(wsb + 0x400000);
    float4* csrG = (float4*)(wsb + 0x800000);

    table_kernel<<<NT, 128, 0, stream>>>(W1, W2, tab, hist);
    pack_kernel<<<NT - 1, 256, 0, stream>>>(tab, tabP);
    hist_kernel<<<(NEDGES + 255) / 256, 256, 0, stream>>>(pos, esrc, edst, hist, actbits);
    scanA_kernel<<<NCHUNK, 256, 0, stream>>>(hist, bsums);
    scanB_kernel<<<1, 256, 0, stream>>>(bsums, bscan);
    scanC_kernel<<<NCHUNK, 256, 0, stream>>>(hist, bscan, row_st, cursor);
    fill_kernel<<<(NEDGES + 255) / 256, 256, 0, stream>>>(pos, esrc, edst, actbits, cursor, csrG, csrS);
    gather_kernel<<<(NNODES + 3) / 4, 256, 0, stream>>>(x, (const float2*)tabP, row_st, csrG, csrS, out);
}